// Round 5
// baseline (145.143 us; speedup 1.0000x reference)
//
#include <hip/hip_runtime.h>
#include <math.h>

#define B_ 4096
#define L_ 50
#define D_ 200
#define A_ 14
#define S_ 30

// ws layout (floats)
#define WS_HYP   0
#define WS_KLE   (A_ * D_)
#define WS_Y2    (2 * A_ * D_)
#define WS_LF    (WS_Y2 + A_)
#define WS_MT    8192            // Mt[200*200]

// ---------- helpers ----------
__device__ __forceinline__ float wave_reduce_sum(float v) {
    #pragma unroll
    for (int off = 32; off > 0; off >>= 1) v += __shfl_down(v, off, 64);
    return v;   // valid in lane 0
}

__device__ __forceinline__ float block_reduce_512(float val, volatile float* red) {
    __syncthreads();
    val = wave_reduce_sum(val);
    if ((threadIdx.x & 63) == 0) red[threadIdx.x >> 6] = val;
    __syncthreads();
    float s = 0.f;
    #pragma unroll
    for (int i = 0; i < 8; ++i) s += red[i];
    return s;
}

// ---------- kernel 0: anchor precompute (tiny) ----------
__global__ __launch_bounds__(256) void precompute_anchors(
    const float* __restrict__ a_emb, const float* __restrict__ seed_w,
    float* __restrict__ ws)
{
    __shared__ float u[A_][D_];
    __shared__ float nrm2[A_];
    const int t = threadIdx.x;
    const int wave = t >> 6, lane = t & 63;

    for (int d = t; d < D_; d += 256) {
        for (int a = 0; a < A_; ++a) {
            float acc = 0.f;
            #pragma unroll 5
            for (int s = 0; s < S_; ++s)
                acc += a_emb[(a * S_ + s) * D_ + d] * seed_w[a * S_ + s];
            u[a][d] = acc;
        }
    }
    __syncthreads();

    for (int a = wave; a < A_; a += 4) {
        float s = 0.f;
        for (int d = lane; d < D_; d += 64) s += u[a][d] * u[a][d];
        s = wave_reduce_sum(s);
        if (lane == 0) nrm2[a] = s;
    }
    __syncthreads();

    float* hyp = ws + WS_HYP;
    float* kle = ws + WS_KLE;
    float* y2  = ws + WS_Y2;
    float* lf  = ws + WS_LF;
    const float maxn = 1.0f - 1e-5f;

    for (int a = 0; a < A_; ++a) {
        float un = fmaxf(sqrtf(nrm2[a]), 1e-15f);
        float th = tanhf(un);
        float pn = fminf(th, maxn);
        float s  = pn / un;
        float py2 = pn * pn;
        float kscale = 2.0f / (1.0f + py2);
        float k2 = py2 * kscale * kscale;
        if (t == 0) {
            y2[a] = py2;
            lf[a] = 1.0f / sqrtf(fmaxf(1.0f - k2, 1e-7f));
        }
        for (int d = t; d < D_; d += 256) {
            float h = u[a][d] * s;
            hyp[a * D_ + d] = h;
            kle[a * D_ + d] = h * kscale;
        }
    }
}

// ---------- kernel 1: Mt = M^T (tiled) ----------
__global__ __launch_bounds__(256) void transpose_M(
    const float* __restrict__ M, float* __restrict__ ws)
{
    __shared__ float tile[16][17];
    float* Mt = ws + WS_MT;
    const int nb = (D_ + 15) / 16;             // 13
    const int bx = blockIdx.x % nb, by = blockIdx.x / nb;
    const int tx = threadIdx.x % 16, ty = threadIdx.x / 16;
    int r = by * 16 + ty, c = bx * 16 + tx;
    if (r < D_ && c < D_) tile[ty][tx] = M[r * D_ + c];
    __syncthreads();
    r = bx * 16 + ty; c = by * 16 + tx;
    if (r < D_ && c < D_) Mt[r * D_ + c] = tile[tx][ty];
}

// ---------- kernel 2: single-gather fully fused pipeline ----------
__global__ __launch_bounds__(512) void fused_one(
    const int*   __restrict__ inputs,
    const float* __restrict__ emb,
    const float* __restrict__ ws,
    float* __restrict__ out)
{
    __shared__ __align__(16) float x[L_][D_];   // 40000 B; rows reused late
    __shared__ __align__(16) float aux[D_];     // sidx -> xavg -> v
    __shared__ float small_[64];                // attn[50], red[8]@52, sums[2]@62

    float* attn = small_;
    float* red  = small_ + 52;
    float* sums = small_ + 62;
    int*   sidx = (int*)aux;

    const float* hyp = ws + WS_HYP;
    const float* kle = ws + WS_KLE;
    const float* y2  = ws + WS_Y2;
    const float* lf  = ws + WS_LF;
    const float* Mt  = ws + WS_MT;

    const int b = blockIdx.x;
    const int t = threadIdx.x;
    const int wave = t >> 6, lane = t & 63;

    if (t < L_) sidx[t] = inputs[b * L_ + t];
    __syncthreads();

    // 1) gather: flat thread-per-float4, 4+1 hand-unrolled batched loads
    {
        const int DQ = D_ / 4;                   // 50
        const int p0 = t, p1 = t + 512, p2 = t + 1024, p3 = t + 1536, p4 = t + 2048;
        const bool has4 = (p4 < L_ * DQ);
        float4 a0 = ((const float4*)(emb + (size_t)sidx[p0 / DQ] * D_))[p0 % DQ];
        float4 a1 = ((const float4*)(emb + (size_t)sidx[p1 / DQ] * D_))[p1 % DQ];
        float4 a2 = ((const float4*)(emb + (size_t)sidx[p2 / DQ] * D_))[p2 % DQ];
        float4 a3 = ((const float4*)(emb + (size_t)sidx[p3 / DQ] * D_))[p3 % DQ];
        float4 a4;
        if (has4) a4 = ((const float4*)(emb + (size_t)sidx[p4 / DQ] * D_))[p4 % DQ];
        ((float4*)x[p0 / DQ])[p0 % DQ] = a0;
        ((float4*)x[p1 / DQ])[p1 % DQ] = a1;
        ((float4*)x[p2 / DQ])[p2 % DQ] = a2;
        ((float4*)x[p3 / DQ])[p3 % DQ] = a3;
        if (has4) ((float4*)x[p4 / DQ])[p4 % DQ] = a4;
    }
    __syncthreads();      // gather done; sidx dead

    // 2) xavg[t] from LDS column sums (overwrites sidx region)
    if (t < D_) {
        float s = 0.f;
        #pragma unroll 10
        for (int l = 0; l < L_; ++l) s += x[l][t];
        aux[t] = s * (1.0f / (float)L_);
    }
    __syncthreads();

    // 3) v = M @ xavg via Mt: thread-per-output, coalesced deep load pipeline,
    //    zero cross-lane ops (R3's failure was 25 serial wave-reduces here)
    float vreg = 0.f;
    if (t < D_) {
        float acc = 0.f;
        #pragma unroll 8
        for (int e = 0; e < D_; ++e)
            acc += Mt[e * D_ + t] * aux[e];      // Mt row e: lanes contiguous
        vreg = acc;
    }
    __syncthreads();      // all xavg reads done
    if (t < D_) aux[t] = vreg;                   // aux now holds v
    __syncthreads();

    // 4) scores: wave per l, dot(x_l, v)
    for (int l = wave; l < L_; l += 8) {
        float s = x[l][lane] * aux[lane] + x[l][lane + 64] * aux[lane + 64]
                + x[l][lane + 128] * aux[lane + 128];
        if (lane < D_ - 192) s += x[l][lane + 192] * aux[lane + 192];
        s = wave_reduce_sum(s);
        if (lane == 0) attn[l] = s;
    }
    __syncthreads();

    // 5) softmax over L (wave 0)
    if (wave == 0) {
        float scv = (lane < L_) ? attn[lane] : -INFINITY;
        float m = scv;
        #pragma unroll
        for (int off = 32; off > 0; off >>= 1) m = fmaxf(m, __shfl_xor(m, off, 64));
        float e = (lane < L_) ? expf(scv - m) : 0.f;
        float ss = e;
        #pragma unroll
        for (int off = 32; off > 0; off >>= 1) ss += __shfl_xor(ss, off, 64);
        if (lane < L_) attn[lane] = e / ss;
    }
    __syncthreads();

    // 6) enc[d]
    float encv = 0.f;
    if (t < D_) {
        #pragma unroll 10
        for (int l = 0; l < L_; ++l) encv += attn[l] * x[l][t];
    }

    // 7) expmap0 + proj
    float n2 = block_reduce_512((t < D_) ? encv * encv : 0.f, red);
    const float maxn = 1.0f - 1e-5f;
    float un = fmaxf(sqrtf(n2), 1e-15f);
    float pn = fminf(tanhf(un), maxn);
    float ps = pn / un;
    float x2 = pn * pn;
    float* pvec  = &x[0][0];          // x dead from here on
    float* dotpq = &x[1][0];
    float* pexp  = &x[1][16];
    float* pe    = &x[1][32];
    if (t < D_) pvec[t] = encv * ps;
    __syncthreads();

    // 8) dot(p, hyp_a): wave per anchor
    for (int a = wave; a < A_; a += 8) {
        const float* ha = hyp + a * D_;
        float s = ha[lane] * pvec[lane] + ha[lane + 64] * pvec[lane + 64]
                + ha[lane + 128] * pvec[lane + 128];
        if (lane < D_ - 192) s += ha[lane + 192] * pvec[lane + 192];
        s = wave_reduce_sum(s);
        if (lane == 0) dotpq[a] = s;
    }
    __syncthreads();

    // 9) sqdist scalars -> probs_exp
    if (t < A_) {
        float dot = dotpq[t];
        float yy  = y2[t];
        float c1 = 1.0f - 2.0f * dot + yy;
        float c2 = 1.0f - x2;
        float num2 = c1 * c1 * x2 - 2.0f * c1 * c2 * dot + c2 * c2 * yy;
        float den  = fmaxf(1.0f - 2.0f * dot + x2 * yy, 1e-15f);
        float nma  = sqrtf(fmaxf(num2, 0.f)) / den;
        float z    = fminf(nma, 1.0f - 1e-7f);
        float dist = logf((1.0f + z) / (1.0f - z));
        pexp[t] = expf(-dist * dist - 0.05f);
    }
    __syncthreads();
    if (t == 0) {
        float se = 0.f, sp = 0.f;
        for (int a = 0; a < A_; ++a) { se += pexp[a]; sp += lf[a] * pexp[a]; }
        sums[0] = 1.0f / se;
        sums[1] = 1.0f / sp;
    }
    __syncthreads();
    if (t < A_) {
        float ap  = pexp[t] * sums[0];
        float pev = lf[t] * pexp[t] * sums[1];
        pe[t] = pev;
        out[B_ * D_ + b * A_ + t] = pev;                 // probs_expanded
        out[B_ * D_ + B_ * A_ + b * A_ + t] = ap;        // a_probs
    }
    __syncthreads();

    // 10) Klein barycenter -> klein_to -> logmap0
    float ko = 0.f;
    if (t < D_) {
        #pragma unroll
        for (int a = 0; a < A_; ++a) ko += kle[a * D_ + t] * pe[a];
    }
    float n2k = block_reduce_512((t < D_) ? ko * ko : 0.f, red);
    if (t < D_) {
        float denom = 1.0f + sqrtf(fmaxf(1.0f - n2k, 0.f));
        float rv = ko / denom;
        float r2 = n2k / (denom * denom);
        float rn = fmaxf(sqrtf(r2), 1e-15f);
        float z  = fminf(rn, 1.0f - 1e-7f);
        float fac = (0.5f * logf((1.0f + z) / (1.0f - z))) / rn;
        out[b * D_ + t] = fac * rv;
    }
}

extern "C" void kernel_launch(void* const* d_in, const int* in_sizes, int n_in,
                              void* d_out, int out_size, void* d_ws, size_t ws_size,
                              hipStream_t stream) {
    (void)in_sizes; (void)n_in; (void)out_size; (void)ws_size;
    const int*   inputs = (const int*)  d_in[0];
    const float* emb    = (const float*)d_in[1];
    const float* M      = (const float*)d_in[2];
    const float* a_emb  = (const float*)d_in[3];
    const float* seed_w = (const float*)d_in[4];
    float* out = (float*)d_out;
    float* ws  = (float*)d_ws;

    precompute_anchors<<<1, 256, 0, stream>>>(a_emb, seed_w, ws);
    const int nb = (D_ + 15) / 16;
    transpose_M<<<nb * nb, 256, 0, stream>>>(M, ws);
    fused_one<<<B_, 512, 0, stream>>>(inputs, emb, ws, out);
}

// Round 6
// 134.127 us; speedup vs baseline: 1.0821x; 1.0821x over previous
//
#include <hip/hip_runtime.h>
#include <hip/hip_fp16.h>
#include <math.h>

#define B_ 4096
#define L_ 50
#define D_ 200
#define A_ 14
#define S_ 30

// ws layout (floats)
#define WS_HYP   0
#define WS_KLE   (A_ * D_)
#define WS_Y2    (2 * A_ * D_)
#define WS_LF    (WS_Y2 + A_)
#define WS_V     8192
#define WS_EMBH  (WS_V + B_ * D_)          // 827392; half-typed region
#define EMBH_FLOATS ((50000 * D_) / 2)     // 5,000,000 floats = 10M halves

// ---------- helpers ----------
__device__ __forceinline__ float wave_reduce_sum(float v) {
    #pragma unroll
    for (int off = 32; off > 0; off >>= 1) v += __shfl_down(v, off, 64);
    return v;   // valid in lane 0
}

__device__ __forceinline__ float block_reduce_512(float val, volatile float* red) {
    __syncthreads();
    val = wave_reduce_sum(val);
    if ((threadIdx.x & 63) == 0) red[threadIdx.x >> 6] = val;
    __syncthreads();
    float s = 0.f;
    #pragma unroll
    for (int i = 0; i < 8; ++i) s += red[i];
    return s;
}

// ---------- kernel 0: anchor precompute (tiny) ----------
__global__ __launch_bounds__(256) void precompute_anchors(
    const float* __restrict__ a_emb, const float* __restrict__ seed_w,
    float* __restrict__ ws)
{
    __shared__ float u[A_][D_];
    __shared__ float nrm2[A_];
    const int t = threadIdx.x;
    const int wave = t >> 6, lane = t & 63;

    for (int d = t; d < D_; d += 256) {
        for (int a = 0; a < A_; ++a) {
            float acc = 0.f;
            #pragma unroll 5
            for (int s = 0; s < S_; ++s)
                acc += a_emb[(a * S_ + s) * D_ + d] * seed_w[a * S_ + s];
            u[a][d] = acc;
        }
    }
    __syncthreads();

    for (int a = wave; a < A_; a += 4) {
        float s = 0.f;
        for (int d = lane; d < D_; d += 64) s += u[a][d] * u[a][d];
        s = wave_reduce_sum(s);
        if (lane == 0) nrm2[a] = s;
    }
    __syncthreads();

    float* hyp = ws + WS_HYP;
    float* kle = ws + WS_KLE;
    float* y2  = ws + WS_Y2;
    float* lf  = ws + WS_LF;
    const float maxn = 1.0f - 1e-5f;

    for (int a = 0; a < A_; ++a) {
        float un = fmaxf(sqrtf(nrm2[a]), 1e-15f);
        float th = tanhf(un);
        float pn = fminf(th, maxn);
        float s  = pn / un;
        float py2 = pn * pn;
        float kscale = 2.0f / (1.0f + py2);
        float k2 = py2 * kscale * kscale;
        if (t == 0) {
            y2[a] = py2;
            lf[a] = 1.0f / sqrtf(fmaxf(1.0f - k2, 1e-7f));
        }
        for (int d = t; d < D_; d += 256) {
            float h = u[a][d] * s;
            hyp[a * D_ + d] = h;
            kle[a * D_ + d] = h * kscale;
        }
    }
}

// ---------- kernel 1: emb f32 -> f16 (streaming) ----------
__global__ __launch_bounds__(256) void convert_emb(
    const float* __restrict__ emb, __half* __restrict__ embh)
{
    const int n4 = (50000 * D_) / 4;           // 2,500,000 float4s
    for (int i = blockIdx.x * 256 + threadIdx.x; i < n4; i += gridDim.x * 256) {
        float4 v = ((const float4*)emb)[i];
        union { __half2 h[2]; uint2 u; } pk;
        pk.h[0] = __floats2half2_rn(v.x, v.y);
        pk.h[1] = __floats2half2_rn(v.z, v.w);
        ((uint2*)embh)[i] = pk.u;
    }
}

// ---------- kernel 2: fp16 gather + xavg + matvec (8 rows/block) ----------
#define G_R 8
__global__ __launch_bounds__(512) void gather_gemm_h(
    const int* __restrict__ inputs, const float* __restrict__ ws_emb,
    const float* __restrict__ M, float* __restrict__ ws)
{
    __shared__ float xs[G_R][D_ + 4];
    __shared__ int sidx[G_R][L_];
    const __half* embh = (const __half*)(ws_emb + WS_EMBH);
    float* v = ws + WS_V;
    const int b0 = blockIdx.x * G_R;
    const int t = threadIdx.x;
    const int wave = t >> 6, lane = t & 63;

    for (int p = t; p < G_R * L_; p += 512) sidx[p / L_][p % L_] = inputs[b0 * L_ + p];
    __syncthreads();

    if (lane < D_ / 4) {
        float ax = 0.f, ay = 0.f, az = 0.f, aw = 0.f;
        #pragma unroll
        for (int l = 0; l < L_; ++l) {
            uint2 u = ((const uint2*)(embh + (size_t)sidx[wave][l] * D_))[lane];
            float2 f0 = __half22float2(*(__half2*)&u.x);
            float2 f1 = __half22float2(*(__half2*)&u.y);
            ax += f0.x; ay += f0.y; az += f1.x; aw += f1.y;
        }
        const float inv = 1.0f / (float)L_;
        xs[wave][4 * lane + 0] = ax * inv;
        xs[wave][4 * lane + 1] = ay * inv;
        xs[wave][4 * lane + 2] = az * inv;
        xs[wave][4 * lane + 3] = aw * inv;
    }
    __syncthreads();

    // matvec: thread (r = t&7, dg = t>>3); 8 batch rows share each M row
    const int r = t & 7, dg = t >> 3;
    const float* xr = xs[r];
    #pragma unroll
    for (int k = 0; k < 4; ++k) {
        const int d = dg + 64 * k;
        if (d < D_) {
            const float4* Mr4 = (const float4*)(M + d * D_);
            float acc = 0.f;
            #pragma unroll
            for (int e = 0; e < D_ / 4; ++e) {
                float4 m4 = Mr4[e];
                acc += m4.x * xr[4*e] + m4.y * xr[4*e+1] + m4.z * xr[4*e+2] + m4.w * xr[4*e+3];
            }
            v[(size_t)(b0 + r) * D_ + d] = acc;
        }
    }
}

// ---------- kernel 3: fused per-row pipeline, fp16 gather ----------
__global__ __launch_bounds__(512) void fused_main_h(
    const int*   __restrict__ inputs,
    const float* __restrict__ ws,
    float* __restrict__ out)
{
    __shared__ __align__(8) __half xh[L_][D_];   // 20000 B
    __shared__ float pvec[D_];
    __shared__ float attn[L_];
    __shared__ int   sidx[L_];
    __shared__ float dotpq[16];
    __shared__ float pexp[16];
    __shared__ float pe[16];
    __shared__ float red[8];
    __shared__ float sums[2];

    const __half* embh = (const __half*)(ws + WS_EMBH);
    const float* hyp = ws + WS_HYP;
    const float* kle = ws + WS_KLE;
    const float* y2  = ws + WS_Y2;
    const float* lf  = ws + WS_LF;
    const float* vg  = ws + WS_V;

    const int b = blockIdx.x;
    const int t = threadIdx.x;
    const int wave = t >> 6, lane = t & 63;

    float vr0 = vg[(size_t)b * D_ + lane];
    float vr1 = vg[(size_t)b * D_ + lane + 64];
    float vr2 = vg[(size_t)b * D_ + lane + 128];
    float vr3 = (lane < D_ - 192) ? vg[(size_t)b * D_ + lane + 192] : 0.f;

    if (t < L_) sidx[t] = inputs[b * L_ + t];
    __syncthreads();

    // 1) gather fp16: flat thread-per-uint2 (4 halves), 4+1 unrolled
    {
        const int CQ = D_ / 4;                   // 50 chunks/row
        const int p0 = t, p1 = t + 512, p2 = t + 1024, p3 = t + 1536, p4 = t + 2048;
        const bool has4 = (p4 < L_ * CQ);
        uint2 a0 = ((const uint2*)(embh + (size_t)sidx[p0 / CQ] * D_))[p0 % CQ];
        uint2 a1 = ((const uint2*)(embh + (size_t)sidx[p1 / CQ] * D_))[p1 % CQ];
        uint2 a2 = ((const uint2*)(embh + (size_t)sidx[p2 / CQ] * D_))[p2 % CQ];
        uint2 a3 = ((const uint2*)(embh + (size_t)sidx[p3 / CQ] * D_))[p3 % CQ];
        uint2 a4;
        if (has4) a4 = ((const uint2*)(embh + (size_t)sidx[p4 / CQ] * D_))[p4 % CQ];
        ((uint2*)xh[p0 / CQ])[p0 % CQ] = a0;
        ((uint2*)xh[p1 / CQ])[p1 % CQ] = a1;
        ((uint2*)xh[p2 / CQ])[p2 % CQ] = a2;
        ((uint2*)xh[p3 / CQ])[p3 % CQ] = a3;
        if (has4) ((uint2*)xh[p4 / CQ])[p4 % CQ] = a4;
    }
    __syncthreads();

    // 2) scores: wave per l, dot(x_l, v)
    for (int l = wave; l < L_; l += 8) {
        float s = __half2float(xh[l][lane]) * vr0
                + __half2float(xh[l][lane + 64]) * vr1
                + __half2float(xh[l][lane + 128]) * vr2;
        if (lane < D_ - 192) s += __half2float(xh[l][lane + 192]) * vr3;
        s = wave_reduce_sum(s);
        if (lane == 0) attn[l] = s;
    }
    __syncthreads();

    // 3) softmax over L (wave 0)
    if (wave == 0) {
        float scv = (lane < L_) ? attn[lane] : -INFINITY;
        float m = scv;
        #pragma unroll
        for (int off = 32; off > 0; off >>= 1) m = fmaxf(m, __shfl_xor(m, off, 64));
        float e = (lane < L_) ? expf(scv - m) : 0.f;
        float ss = e;
        #pragma unroll
        for (int off = 32; off > 0; off >>= 1) ss += __shfl_xor(ss, off, 64);
        if (lane < L_) attn[lane] = e / ss;
    }
    __syncthreads();

    // 4) enc[d]
    float encv = 0.f;
    if (t < D_) {
        #pragma unroll 10
        for (int l = 0; l < L_; ++l) encv += attn[l] * __half2float(xh[l][t]);
    }

    // 5) expmap0 + proj
    float n2 = block_reduce_512((t < D_) ? encv * encv : 0.f, red);
    const float maxn = 1.0f - 1e-5f;
    float un = fmaxf(sqrtf(n2), 1e-15f);
    float pn = fminf(tanhf(un), maxn);
    float ps = pn / un;
    float x2 = pn * pn;
    if (t < D_) pvec[t] = encv * ps;
    __syncthreads();

    // 6) dot(p, hyp_a): wave per anchor
    for (int a = wave; a < A_; a += 8) {
        const float* ha = hyp + a * D_;
        float s = ha[lane] * pvec[lane] + ha[lane + 64] * pvec[lane + 64]
                + ha[lane + 128] * pvec[lane + 128];
        if (lane < D_ - 192) s += ha[lane + 192] * pvec[lane + 192];
        s = wave_reduce_sum(s);
        if (lane == 0) dotpq[a] = s;
    }
    __syncthreads();

    // 7) sqdist scalars -> probs_exp
    if (t < A_) {
        float dot = dotpq[t];
        float yy  = y2[t];
        float c1 = 1.0f - 2.0f * dot + yy;
        float c2 = 1.0f - x2;
        float num2 = c1 * c1 * x2 - 2.0f * c1 * c2 * dot + c2 * c2 * yy;
        float den  = fmaxf(1.0f - 2.0f * dot + x2 * yy, 1e-15f);
        float nma  = sqrtf(fmaxf(num2, 0.f)) / den;
        float z    = fminf(nma, 1.0f - 1e-7f);
        float dist = logf((1.0f + z) / (1.0f - z));
        pexp[t] = expf(-dist * dist - 0.05f);
    }
    __syncthreads();
    if (t == 0) {
        float se = 0.f, sp = 0.f;
        for (int a = 0; a < A_; ++a) { se += pexp[a]; sp += lf[a] * pexp[a]; }
        sums[0] = 1.0f / se;
        sums[1] = 1.0f / sp;
    }
    __syncthreads();
    if (t < A_) {
        float ap  = pexp[t] * sums[0];
        float pev = lf[t] * pexp[t] * sums[1];
        pe[t] = pev;
        out[B_ * D_ + b * A_ + t] = pev;                 // probs_expanded
        out[B_ * D_ + B_ * A_ + b * A_ + t] = ap;        // a_probs
    }
    __syncthreads();

    // 8) Klein barycenter -> klein_to -> logmap0
    float ko = 0.f;
    if (t < D_) {
        #pragma unroll
        for (int a = 0; a < A_; ++a) ko += kle[a * D_ + t] * pe[a];
    }
    float n2k = block_reduce_512((t < D_) ? ko * ko : 0.f, red);
    if (t < D_) {
        float denom = 1.0f + sqrtf(fmaxf(1.0f - n2k, 0.f));
        float rv = ko / denom;
        float r2 = n2k / (denom * denom);
        float rn = fmaxf(sqrtf(r2), 1e-15f);
        float z  = fminf(rn, 1.0f - 1e-7f);
        float fac = (0.5f * logf((1.0f + z) / (1.0f - z))) / rn;
        out[b * D_ + t] = fac * rv;
    }
}

// ================= fallback f32 path (R4, proven) =================
__global__ __launch_bounds__(512) void gather_gemm(
    const int* __restrict__ inputs, const float* __restrict__ emb,
    const float* __restrict__ M, float* __restrict__ ws)
{
    __shared__ __align__(16) float xs[G_R][D_ + 4];
    __shared__ int sidx[G_R][L_];
    float* v = ws + WS_V;
    const int b0 = blockIdx.x * G_R;
    const int t = threadIdx.x;
    const int wave = t >> 6, lane = t & 63;

    for (int p = t; p < G_R * L_; p += 512) sidx[p / L_][p % L_] = inputs[b0 * L_ + p];
    __syncthreads();

    if (lane < D_ / 4) {
        float ax = 0.f, ay = 0.f, az = 0.f, aw = 0.f;
        #pragma unroll
        for (int l = 0; l < L_; ++l) {
            const float4 vv = ((const float4*)(emb + (size_t)sidx[wave][l] * D_))[lane];
            ax += vv.x; ay += vv.y; az += vv.z; aw += vv.w;
        }
        const float inv = 1.0f / (float)L_;
        ((float4*)xs[wave])[lane] = make_float4(ax * inv, ay * inv, az * inv, aw * inv);
    }
    __syncthreads();

    const int r = t & 7, dg = t >> 3;
    const float4* xr4 = (const float4*)xs[r];
    #pragma unroll
    for (int k = 0; k < 4; ++k) {
        const int d = dg + 64 * k;
        if (d < D_) {
            const float4* Mr4 = (const float4*)(M + d * D_);
            float acc = 0.f;
            #pragma unroll
            for (int e = 0; e < D_ / 4; ++e) {
                float4 m4 = Mr4[e], x4 = xr4[e];
                acc += m4.x * x4.x + m4.y * x4.y + m4.z * x4.z + m4.w * x4.w;
            }
            v[(size_t)(b0 + r) * D_ + d] = acc;
        }
    }
}

__global__ __launch_bounds__(512, 8) void fused_main(
    const int*   __restrict__ inputs,
    const float* __restrict__ emb,
    const float* __restrict__ ws,
    float* __restrict__ out)
{
    __shared__ __align__(16) float x[L_][D_];
    __shared__ float attn[L_];
    __shared__ int   sidx[L_];
    __shared__ float red[8];
    __shared__ float sums[2];

    const float* hyp = ws + WS_HYP;
    const float* kle = ws + WS_KLE;
    const float* y2  = ws + WS_Y2;
    const float* lf  = ws + WS_LF;
    const float* vg  = ws + WS_V;

    const int b = blockIdx.x;
    const int t = threadIdx.x;
    const int wave = t >> 6, lane = t & 63;

    float vr0 = vg[(size_t)b * D_ + lane];
    float vr1 = vg[(size_t)b * D_ + lane + 64];
    float vr2 = vg[(size_t)b * D_ + lane + 128];
    float vr3 = (lane < D_ - 192) ? vg[(size_t)b * D_ + lane + 192] : 0.f;

    if (t < L_) sidx[t] = inputs[b * L_ + t];
    __syncthreads();

    {
        const int DQ = D_ / 4;
        const int p0 = t, p1 = t + 512, p2 = t + 1024, p3 = t + 1536, p4 = t + 2048;
        const bool has4 = (p4 < L_ * DQ);
        float4 a0 = ((const float4*)(emb + (size_t)sidx[p0 / DQ] * D_))[p0 % DQ];
        float4 a1 = ((const float4*)(emb + (size_t)sidx[p1 / DQ] * D_))[p1 % DQ];
        float4 a2 = ((const float4*)(emb + (size_t)sidx[p2 / DQ] * D_))[p2 % DQ];
        float4 a3 = ((const float4*)(emb + (size_t)sidx[p3 / DQ] * D_))[p3 % DQ];
        float4 a4;
        if (has4) a4 = ((const float4*)(emb + (size_t)sidx[p4 / DQ] * D_))[p4 % DQ];
        ((float4*)x[p0 / DQ])[p0 % DQ] = a0;
        ((float4*)x[p1 / DQ])[p1 % DQ] = a1;
        ((float4*)x[p2 / DQ])[p2 % DQ] = a2;
        ((float4*)x[p3 / DQ])[p3 % DQ] = a3;
        if (has4) ((float4*)x[p4 / DQ])[p4 % DQ] = a4;
    }
    __syncthreads();

    for (int l = wave; l < L_; l += 8) {
        float s = x[l][lane] * vr0 + x[l][lane + 64] * vr1 + x[l][lane + 128] * vr2;
        if (lane < D_ - 192) s += x[l][lane + 192] * vr3;
        s = wave_reduce_sum(s);
        if (lane == 0) attn[l] = s;
    }
    __syncthreads();

    if (wave == 0) {
        float scv = (lane < L_) ? attn[lane] : -INFINITY;
        float m = scv;
        #pragma unroll
        for (int off = 32; off > 0; off >>= 1) m = fmaxf(m, __shfl_xor(m, off, 64));
        float e = (lane < L_) ? expf(scv - m) : 0.f;
        float ss = e;
        #pragma unroll
        for (int off = 32; off > 0; off >>= 1) ss += __shfl_xor(ss, off, 64);
        if (lane < L_) attn[lane] = e / ss;
    }
    __syncthreads();

    float encv = 0.f;
    if (t < D_) {
        #pragma unroll 10
        for (int l = 0; l < L_; ++l) encv += attn[l] * x[l][t];
    }

    float n2 = block_reduce_512((t < D_) ? encv * encv : 0.f, red);
    const float maxn = 1.0f - 1e-5f;
    float un = fmaxf(sqrtf(n2), 1e-15f);
    float pn = fminf(tanhf(un), maxn);
    float ps = pn / un;
    float x2 = pn * pn;
    float* pvec  = &x[0][0];
    float* dotpq = &x[1][0];
    float* pexp  = &x[1][16];
    float* pe    = &x[1][32];
    if (t < D_) pvec[t] = encv * ps;
    __syncthreads();

    for (int a = wave; a < A_; a += 8) {
        const float* ha = hyp + a * D_;
        float s = ha[lane] * pvec[lane] + ha[lane + 64] * pvec[lane + 64]
                + ha[lane + 128] * pvec[lane + 128];
        if (lane < D_ - 192) s += ha[lane + 192] * pvec[lane + 192];
        s = wave_reduce_sum(s);
        if (lane == 0) dotpq[a] = s;
    }
    __syncthreads();

    if (t < A_) {
        float dot = dotpq[t];
        float yy  = y2[t];
        float c1 = 1.0f - 2.0f * dot + yy;
        float c2 = 1.0f - x2;
        float num2 = c1 * c1 * x2 - 2.0f * c1 * c2 * dot + c2 * c2 * yy;
        float den  = fmaxf(1.0f - 2.0f * dot + x2 * yy, 1e-15f);
        float nma  = sqrtf(fmaxf(num2, 0.f)) / den;
        float z    = fminf(nma, 1.0f - 1e-7f);
        float dist = logf((1.0f + z) / (1.0f - z));
        pexp[t] = expf(-dist * dist - 0.05f);
    }
    __syncthreads();
    if (t == 0) {
        float se = 0.f, sp = 0.f;
        for (int a = 0; a < A_; ++a) { se += pexp[a]; sp += lf[a] * pexp[a]; }
        sums[0] = 1.0f / se;
        sums[1] = 1.0f / sp;
    }
    __syncthreads();
    if (t < A_) {
        float ap  = pexp[t] * sums[0];
        float pev = lf[t] * pexp[t] * sums[1];
        pe[t] = pev;
        out[B_ * D_ + b * A_ + t] = pev;
        out[B_ * D_ + B_ * A_ + b * A_ + t] = ap;
    }
    __syncthreads();

    float ko = 0.f;
    if (t < D_) {
        #pragma unroll
        for (int a = 0; a < A_; ++a) ko += kle[a * D_ + t] * pe[a];
    }
    float n2k = block_reduce_512((t < D_) ? ko * ko : 0.f, red);
    if (t < D_) {
        float denom = 1.0f + sqrtf(fmaxf(1.0f - n2k, 0.f));
        float rv = ko / denom;
        float r2 = n2k / (denom * denom);
        float rn = fmaxf(sqrtf(r2), 1e-15f);
        float z  = fminf(rn, 1.0f - 1e-7f);
        float fac = (0.5f * logf((1.0f + z) / (1.0f - z))) / rn;
        out[b * D_ + t] = fac * rv;
    }
}

extern "C" void kernel_launch(void* const* d_in, const int* in_sizes, int n_in,
                              void* d_out, int out_size, void* d_ws, size_t ws_size,
                              hipStream_t stream) {
    (void)in_sizes; (void)n_in; (void)out_size;
    const int*   inputs = (const int*)  d_in[0];
    const float* emb    = (const float*)d_in[1];
    const float* M      = (const float*)d_in[2];
    const float* a_emb  = (const float*)d_in[3];
    const float* seed_w = (const float*)d_in[4];
    float* out = (float*)d_out;
    float* ws  = (float*)d_ws;

    precompute_anchors<<<1, 256, 0, stream>>>(a_emb, seed_w, ws);

    const size_t need = (size_t)(WS_EMBH + EMBH_FLOATS) * sizeof(float);
    if (ws_size >= need) {
        __half* embh = (__half*)(ws + WS_EMBH);
        convert_emb<<<2048, 256, 0, stream>>>(emb, embh);
        gather_gemm_h<<<B_ / G_R, 512, 0, stream>>>(inputs, ws, M, ws);
        fused_main_h<<<B_, 512, 0, stream>>>(inputs, ws, out);
    } else {
        gather_gemm<<<B_ / G_R, 512, 0, stream>>>(inputs, emb, M, ws);
        fused_main<<<B_, 512, 0, stream>>>(inputs, emb, ws, out);
    }
}

// Round 7
// 133.438 us; speedup vs baseline: 1.0877x; 1.0052x over previous
//
#include <hip/hip_runtime.h>
#include <hip/hip_fp16.h>
#include <math.h>

#define B_ 4096
#define L_ 50
#define D_ 200
#define A_ 14
#define S_ 30

// ws layout (floats)
#define WS_HYP   0
#define WS_KLE   (A_ * D_)
#define WS_Y2    (2 * A_ * D_)
#define WS_LF    (WS_Y2 + A_)
#define WS_V     8192
#define WS_EMBH  (WS_V + B_ * D_)          // 827392; half-typed region
#define EMBH_FLOATS ((50000 * D_) / 2)     // 5,000,000 floats = 10M halves

// ---------- helpers ----------
__device__ __forceinline__ float wave_reduce_sum(float v) {
    #pragma unroll
    for (int off = 32; off > 0; off >>= 1) v += __shfl_down(v, off, 64);
    return v;   // valid in lane 0
}

__device__ __forceinline__ float block_reduce_512(float val, volatile float* red) {
    __syncthreads();
    val = wave_reduce_sum(val);
    if ((threadIdx.x & 63) == 0) red[threadIdx.x >> 6] = val;
    __syncthreads();
    float s = 0.f;
    #pragma unroll
    for (int i = 0; i < 8; ++i) s += red[i];
    return s;
}

// ---------- kernel 0: anchor precompute (tiny) ----------
__global__ __launch_bounds__(256) void precompute_anchors(
    const float* __restrict__ a_emb, const float* __restrict__ seed_w,
    float* __restrict__ ws)
{
    __shared__ float u[A_][D_];
    __shared__ float nrm2[A_];
    const int t = threadIdx.x;
    const int wave = t >> 6, lane = t & 63;

    for (int d = t; d < D_; d += 256) {
        for (int a = 0; a < A_; ++a) {
            float acc = 0.f;
            #pragma unroll 5
            for (int s = 0; s < S_; ++s)
                acc += a_emb[(a * S_ + s) * D_ + d] * seed_w[a * S_ + s];
            u[a][d] = acc;
        }
    }
    __syncthreads();

    for (int a = wave; a < A_; a += 4) {
        float s = 0.f;
        for (int d = lane; d < D_; d += 64) s += u[a][d] * u[a][d];
        s = wave_reduce_sum(s);
        if (lane == 0) nrm2[a] = s;
    }
    __syncthreads();

    float* hyp = ws + WS_HYP;
    float* kle = ws + WS_KLE;
    float* y2  = ws + WS_Y2;
    float* lf  = ws + WS_LF;
    const float maxn = 1.0f - 1e-5f;

    for (int a = 0; a < A_; ++a) {
        float un = fmaxf(sqrtf(nrm2[a]), 1e-15f);
        float th = tanhf(un);
        float pn = fminf(th, maxn);
        float s  = pn / un;
        float py2 = pn * pn;
        float kscale = 2.0f / (1.0f + py2);
        float k2 = py2 * kscale * kscale;
        if (t == 0) {
            y2[a] = py2;
            lf[a] = 1.0f / sqrtf(fmaxf(1.0f - k2, 1e-7f));
        }
        for (int d = t; d < D_; d += 256) {
            float h = u[a][d] * s;
            hyp[a * D_ + d] = h;
            kle[a * D_ + d] = h * kscale;
        }
    }
}

// ---------- kernel 1: emb f32 -> f16 (streaming) ----------
__global__ __launch_bounds__(256) void convert_emb(
    const float* __restrict__ emb, __half* __restrict__ embh)
{
    const int n4 = (50000 * D_) / 4;           // 2,500,000 float4s
    for (int i = blockIdx.x * 256 + threadIdx.x; i < n4; i += gridDim.x * 256) {
        float4 v = ((const float4*)emb)[i];
        union { __half2 h[2]; uint2 u; } pk;
        pk.h[0] = __floats2half2_rn(v.x, v.y);
        pk.h[1] = __floats2half2_rn(v.z, v.w);
        ((uint2*)embh)[i] = pk.u;
    }
}

// ---------- kernel 2: fp16 gather + xavg + matvec (8 rows/block) ----------
#define G_R 8
__global__ __launch_bounds__(512) void gather_gemm_h(
    const int* __restrict__ inputs, const float* __restrict__ ws_emb,
    const float* __restrict__ M, float* __restrict__ ws)
{
    __shared__ float xs[G_R][D_ + 4];
    __shared__ int sidx[G_R][L_];
    const __half* embh = (const __half*)(ws_emb + WS_EMBH);
    float* v = ws + WS_V;
    const int b0 = blockIdx.x * G_R;
    const int t = threadIdx.x;

    for (int p = t; p < G_R * L_; p += 512) sidx[p / L_][p % L_] = inputs[b0 * L_ + p];
    __syncthreads();

    // gather+mean: thread (br, c) accumulates uint4 chunk c (8 halves) over 50 rows
    if (t < G_R * 25) {
        const int br = t / 25, c = t % 25;
        float acc[8] = {0.f,0.f,0.f,0.f,0.f,0.f,0.f,0.f};
        #pragma unroll
        for (int l = 0; l < L_; ++l) {
            uint4 u = ((const uint4*)(embh + (size_t)sidx[br][l] * D_))[c];
            const __half2* h2 = (const __half2*)&u;
            #pragma unroll
            for (int k = 0; k < 4; ++k) {
                float2 f = __half22float2(h2[k]);
                acc[2*k]   += f.x;
                acc[2*k+1] += f.y;
            }
        }
        const float inv = 1.0f / (float)L_;
        #pragma unroll
        for (int k = 0; k < 8; ++k) xs[br][8*c + k] = acc[k] * inv;
    }
    __syncthreads();

    // matvec: thread (r = t&7, dg = t>>3); 8 batch rows share each M row
    const int r = t & 7, dg = t >> 3;
    const float* xr = xs[r];
    #pragma unroll
    for (int k = 0; k < 4; ++k) {
        const int d = dg + 64 * k;
        if (d < D_) {
            const float4* Mr4 = (const float4*)(M + d * D_);
            float acc = 0.f;
            #pragma unroll
            for (int e = 0; e < D_ / 4; ++e) {
                float4 m4 = Mr4[e];
                acc += m4.x * xr[4*e] + m4.y * xr[4*e+1] + m4.z * xr[4*e+2] + m4.w * xr[4*e+3];
            }
            v[(size_t)(b0 + r) * D_ + d] = acc;
        }
    }
}

// ---------- kernel 3: fused per-row pipeline, fp16 uint4 gather ----------
__global__ __launch_bounds__(512) void fused_main_h(
    const int*   __restrict__ inputs,
    const float* __restrict__ ws,
    float* __restrict__ out)
{
    __shared__ __align__(16) __half xh[L_][D_];   // 20000 B
    __shared__ float pvec[D_];
    __shared__ float attn[L_];
    __shared__ int   sidx[L_];
    __shared__ float dotpq[16];
    __shared__ float pexp[16];
    __shared__ float pe[16];
    __shared__ float red[8];
    __shared__ float sums[2];

    const __half* embh = (const __half*)(ws + WS_EMBH);
    const float* hyp = ws + WS_HYP;
    const float* kle = ws + WS_KLE;
    const float* y2  = ws + WS_Y2;
    const float* lf  = ws + WS_LF;
    const float* vg  = ws + WS_V;

    const int b = blockIdx.x;
    const int t = threadIdx.x;
    const int wave = t >> 6, lane = t & 63;

    float vr0 = vg[(size_t)b * D_ + lane];
    float vr1 = vg[(size_t)b * D_ + lane + 64];
    float vr2 = vg[(size_t)b * D_ + lane + 128];
    float vr3 = (lane < D_ - 192) ? vg[(size_t)b * D_ + lane + 192] : 0.f;

    if (t < L_) sidx[t] = inputs[b * L_ + t];
    __syncthreads();

    // 1) gather fp16: 1250 uint4 chunks (16B = 8 halves), 2-3 per thread
    {
        uint4* dst = (uint4*)&xh[0][0];
        const int p0 = t, p1 = t + 512, p2 = t + 1024;
        const bool has2 = (p2 < L_ * 25);
        uint4 a0 = ((const uint4*)(embh + (size_t)sidx[p0 / 25] * D_))[p0 % 25];
        uint4 a1 = ((const uint4*)(embh + (size_t)sidx[p1 / 25] * D_))[p1 % 25];
        uint4 a2;
        if (has2) a2 = ((const uint4*)(embh + (size_t)sidx[p2 / 25] * D_))[p2 % 25];
        dst[p0] = a0;
        dst[p1] = a1;
        if (has2) dst[p2] = a2;
    }
    __syncthreads();

    // 2) scores: wave per l, dot(x_l, v)
    for (int l = wave; l < L_; l += 8) {
        float s = __half2float(xh[l][lane]) * vr0
                + __half2float(xh[l][lane + 64]) * vr1
                + __half2float(xh[l][lane + 128]) * vr2;
        if (lane < D_ - 192) s += __half2float(xh[l][lane + 192]) * vr3;
        s = wave_reduce_sum(s);
        if (lane == 0) attn[l] = s;
    }
    __syncthreads();

    // 3) softmax over L (wave 0)
    if (wave == 0) {
        float scv = (lane < L_) ? attn[lane] : -INFINITY;
        float m = scv;
        #pragma unroll
        for (int off = 32; off > 0; off >>= 1) m = fmaxf(m, __shfl_xor(m, off, 64));
        float e = (lane < L_) ? expf(scv - m) : 0.f;
        float ss = e;
        #pragma unroll
        for (int off = 32; off > 0; off >>= 1) ss += __shfl_xor(ss, off, 64);
        if (lane < L_) attn[lane] = e / ss;
    }
    __syncthreads();

    // 4) enc[d]
    float encv = 0.f;
    if (t < D_) {
        #pragma unroll 10
        for (int l = 0; l < L_; ++l) encv += attn[l] * __half2float(xh[l][t]);
    }

    // 5) expmap0 + proj
    float n2 = block_reduce_512((t < D_) ? encv * encv : 0.f, red);
    const float maxn = 1.0f - 1e-5f;
    float un = fmaxf(sqrtf(n2), 1e-15f);
    float pn = fminf(tanhf(un), maxn);
    float ps = pn / un;
    float x2 = pn * pn;
    if (t < D_) pvec[t] = encv * ps;
    __syncthreads();

    // 6) dot(p, hyp_a): wave per anchor
    for (int a = wave; a < A_; a += 8) {
        const float* ha = hyp + a * D_;
        float s = ha[lane] * pvec[lane] + ha[lane + 64] * pvec[lane + 64]
                + ha[lane + 128] * pvec[lane + 128];
        if (lane < D_ - 192) s += ha[lane + 192] * pvec[lane + 192];
        s = wave_reduce_sum(s);
        if (lane == 0) dotpq[a] = s;
    }
    __syncthreads();

    // 7) sqdist scalars -> probs_exp
    if (t < A_) {
        float dot = dotpq[t];
        float yy  = y2[t];
        float c1 = 1.0f - 2.0f * dot + yy;
        float c2 = 1.0f - x2;
        float num2 = c1 * c1 * x2 - 2.0f * c1 * c2 * dot + c2 * c2 * yy;
        float den  = fmaxf(1.0f - 2.0f * dot + x2 * yy, 1e-15f);
        float nma  = sqrtf(fmaxf(num2, 0.f)) / den;
        float z    = fminf(nma, 1.0f - 1e-7f);
        float dist = logf((1.0f + z) / (1.0f - z));
        pexp[t] = expf(-dist * dist - 0.05f);
    }
    __syncthreads();
    if (t == 0) {
        float se = 0.f, sp = 0.f;
        for (int a = 0; a < A_; ++a) { se += pexp[a]; sp += lf[a] * pexp[a]; }
        sums[0] = 1.0f / se;
        sums[1] = 1.0f / sp;
    }
    __syncthreads();
    if (t < A_) {
        float ap  = pexp[t] * sums[0];
        float pev = lf[t] * pexp[t] * sums[1];
        pe[t] = pev;
        out[B_ * D_ + b * A_ + t] = pev;                 // probs_expanded
        out[B_ * D_ + B_ * A_ + b * A_ + t] = ap;        // a_probs
    }
    __syncthreads();

    // 8) Klein barycenter -> klein_to -> logmap0
    float ko = 0.f;
    if (t < D_) {
        #pragma unroll
        for (int a = 0; a < A_; ++a) ko += kle[a * D_ + t] * pe[a];
    }
    float n2k = block_reduce_512((t < D_) ? ko * ko : 0.f, red);
    if (t < D_) {
        float denom = 1.0f + sqrtf(fmaxf(1.0f - n2k, 0.f));
        float rv = ko / denom;
        float r2 = n2k / (denom * denom);
        float rn = fmaxf(sqrtf(r2), 1e-15f);
        float z  = fminf(rn, 1.0f - 1e-7f);
        float fac = (0.5f * logf((1.0f + z) / (1.0f - z))) / rn;
        out[b * D_ + t] = fac * rv;
    }
}

// ================= fallback f32 path (R4, proven) =================
__global__ __launch_bounds__(512) void gather_gemm(
    const int* __restrict__ inputs, const float* __restrict__ emb,
    const float* __restrict__ M, float* __restrict__ ws)
{
    __shared__ __align__(16) float xs[G_R][D_ + 4];
    __shared__ int sidx[G_R][L_];
    float* v = ws + WS_V;
    const int b0 = blockIdx.x * G_R;
    const int t = threadIdx.x;
    const int wave = t >> 6, lane = t & 63;

    for (int p = t; p < G_R * L_; p += 512) sidx[p / L_][p % L_] = inputs[b0 * L_ + p];
    __syncthreads();

    if (lane < D_ / 4) {
        float ax = 0.f, ay = 0.f, az = 0.f, aw = 0.f;
        #pragma unroll
        for (int l = 0; l < L_; ++l) {
            const float4 vv = ((const float4*)(emb + (size_t)sidx[wave][l] * D_))[lane];
            ax += vv.x; ay += vv.y; az += vv.z; aw += vv.w;
        }
        const float inv = 1.0f / (float)L_;
        ((float4*)xs[wave])[lane] = make_float4(ax * inv, ay * inv, az * inv, aw * inv);
    }
    __syncthreads();

    const int r = t & 7, dg = t >> 3;
    const float4* xr4 = (const float4*)xs[r];
    #pragma unroll
    for (int k = 0; k < 4; ++k) {
        const int d = dg + 64 * k;
        if (d < D_) {
            const float4* Mr4 = (const float4*)(M + d * D_);
            float acc = 0.f;
            #pragma unroll
            for (int e = 0; e < D_ / 4; ++e) {
                float4 m4 = Mr4[e], x4 = xr4[e];
                acc += m4.x * x4.x + m4.y * x4.y + m4.z * x4.z + m4.w * x4.w;
            }
            v[(size_t)(b0 + r) * D_ + d] = acc;
        }
    }
}

__global__ __launch_bounds__(512, 8) void fused_main(
    const int*   __restrict__ inputs,
    const float* __restrict__ emb,
    const float* __restrict__ ws,
    float* __restrict__ out)
{
    __shared__ __align__(16) float x[L_][D_];
    __shared__ float attn[L_];
    __shared__ int   sidx[L_];
    __shared__ float red[8];
    __shared__ float sums[2];

    const float* hyp = ws + WS_HYP;
    const float* kle = ws + WS_KLE;
    const float* y2  = ws + WS_Y2;
    const float* lf  = ws + WS_LF;
    const float* vg  = ws + WS_V;

    const int b = blockIdx.x;
    const int t = threadIdx.x;
    const int wave = t >> 6, lane = t & 63;

    float vr0 = vg[(size_t)b * D_ + lane];
    float vr1 = vg[(size_t)b * D_ + lane + 64];
    float vr2 = vg[(size_t)b * D_ + lane + 128];
    float vr3 = (lane < D_ - 192) ? vg[(size_t)b * D_ + lane + 192] : 0.f;

    if (t < L_) sidx[t] = inputs[b * L_ + t];
    __syncthreads();

    {
        const int DQ = D_ / 4;
        const int p0 = t, p1 = t + 512, p2 = t + 1024, p3 = t + 1536, p4 = t + 2048;
        const bool has4 = (p4 < L_ * DQ);
        float4 a0 = ((const float4*)(emb + (size_t)sidx[p0 / DQ] * D_))[p0 % DQ];
        float4 a1 = ((const float4*)(emb + (size_t)sidx[p1 / DQ] * D_))[p1 % DQ];
        float4 a2 = ((const float4*)(emb + (size_t)sidx[p2 / DQ] * D_))[p2 % DQ];
        float4 a3 = ((const float4*)(emb + (size_t)sidx[p3 / DQ] * D_))[p3 % DQ];
        float4 a4;
        if (has4) a4 = ((const float4*)(emb + (size_t)sidx[p4 / DQ] * D_))[p4 % DQ];
        ((float4*)x[p0 / DQ])[p0 % DQ] = a0;
        ((float4*)x[p1 / DQ])[p1 % DQ] = a1;
        ((float4*)x[p2 / DQ])[p2 % DQ] = a2;
        ((float4*)x[p3 / DQ])[p3 % DQ] = a3;
        if (has4) ((float4*)x[p4 / DQ])[p4 % DQ] = a4;
    }
    __syncthreads();

    for (int l = wave; l < L_; l += 8) {
        float s = x[l][lane] * vr0 + x[l][lane + 64] * vr1 + x[l][lane + 128] * vr2;
        if (lane < D_ - 192) s += x[l][lane + 192] * vr3;
        s = wave_reduce_sum(s);
        if (lane == 0) attn[l] = s;
    }
    __syncthreads();

    if (wave == 0) {
        float scv = (lane < L_) ? attn[lane] : -INFINITY;
        float m = scv;
        #pragma unroll
        for (int off = 32; off > 0; off >>= 1) m = fmaxf(m, __shfl_xor(m, off, 64));
        float e = (lane < L_) ? expf(scv - m) : 0.f;
        float ss = e;
        #pragma unroll
        for (int off = 32; off > 0; off >>= 1) ss += __shfl_xor(ss, off, 64);
        if (lane < L_) attn[lane] = e / ss;
    }
    __syncthreads();

    float encv = 0.f;
    if (t < D_) {
        #pragma unroll 10
        for (int l = 0; l < L_; ++l) encv += attn[l] * x[l][t];
    }

    float n2 = block_reduce_512((t < D_) ? encv * encv : 0.f, red);
    const float maxn = 1.0f - 1e-5f;
    float un = fmaxf(sqrtf(n2), 1e-15f);
    float pn = fminf(tanhf(un), maxn);
    float ps = pn / un;
    float x2 = pn * pn;
    float* pvec  = &x[0][0];
    float* dotpq = &x[1][0];
    float* pexp  = &x[1][16];
    float* pe    = &x[1][32];
    if (t < D_) pvec[t] = encv * ps;
    __syncthreads();

    for (int a = wave; a < A_; a += 8) {
        const float* ha = hyp + a * D_;
        float s = ha[lane] * pvec[lane] + ha[lane + 64] * pvec[lane + 64]
                + ha[lane + 128] * pvec[lane + 128];
        if (lane < D_ - 192) s += ha[lane + 192] * pvec[lane + 192];
        s = wave_reduce_sum(s);
        if (lane == 0) dotpq[a] = s;
    }
    __syncthreads();

    if (t < A_) {
        float dot = dotpq[t];
        float yy  = y2[t];
        float c1 = 1.0f - 2.0f * dot + yy;
        float c2 = 1.0f - x2;
        float num2 = c1 * c1 * x2 - 2.0f * c1 * c2 * dot + c2 * c2 * yy;
        float den  = fmaxf(1.0f - 2.0f * dot + x2 * yy, 1e-15f);
        float nma  = sqrtf(fmaxf(num2, 0.f)) / den;
        float z    = fminf(nma, 1.0f - 1e-7f);
        float dist = logf((1.0f + z) / (1.0f - z));
        pexp[t] = expf(-dist * dist - 0.05f);
    }
    __syncthreads();
    if (t == 0) {
        float se = 0.f, sp = 0.f;
        for (int a = 0; a < A_; ++a) { se += pexp[a]; sp += lf[a] * pexp[a]; }
        sums[0] = 1.0f / se;
        sums[1] = 1.0f / sp;
    }
    __syncthreads();
    if (t < A_) {
        float ap  = pexp[t] * sums[0];
        float pev = lf[t] * pexp[t] * sums[1];
        pe[t] = pev;
        out[B_ * D_ + b * A_ + t] = pev;
        out[B_ * D_ + B_ * A_ + b * A_ + t] = ap;
    }
    __syncthreads();

    float ko = 0.f;
    if (t < D_) {
        #pragma unroll
        for (int a = 0; a < A_; ++a) ko += kle[a * D_ + t] * pe[a];
    }
    float n2k = block_reduce_512((t < D_) ? ko * ko : 0.f, red);
    if (t < D_) {
        float denom = 1.0f + sqrtf(fmaxf(1.0f - n2k, 0.f));
        float rv = ko / denom;
        float r2 = n2k / (denom * denom);
        float rn = fmaxf(sqrtf(r2), 1e-15f);
        float z  = fminf(rn, 1.0f - 1e-7f);
        float fac = (0.5f * logf((1.0f + z) / (1.0f - z))) / rn;
        out[b * D_ + t] = fac * rv;
    }
}

extern "C" void kernel_launch(void* const* d_in, const int* in_sizes, int n_in,
                              void* d_out, int out_size, void* d_ws, size_t ws_size,
                              hipStream_t stream) {
    (void)in_sizes; (void)n_in; (void)out_size;
    const int*   inputs = (const int*)  d_in[0];
    const float* emb    = (const float*)d_in[1];
    const float* M      = (const float*)d_in[2];
    const float* a_emb  = (const float*)d_in[3];
    const float* seed_w = (const float*)d_in[4];
    float* out = (float*)d_out;
    float* ws  = (float*)d_ws;

    precompute_anchors<<<1, 256, 0, stream>>>(a_emb, seed_w, ws);

    const size_t need = (size_t)(WS_EMBH + EMBH_FLOATS) * sizeof(float);
    if (ws_size >= need) {
        __half* embh = (__half*)(ws + WS_EMBH);
        convert_emb<<<2048, 256, 0, stream>>>(emb, embh);
        gather_gemm_h<<<B_ / G_R, 512, 0, stream>>>(inputs, ws, M, ws);
        fused_main_h<<<B_, 512, 0, stream>>>(inputs, ws, out);
    } else {
        gather_gemm<<<B_ / G_R, 512, 0, stream>>>(inputs, emb, M, ws);
        fused_main<<<B_, 512, 0, stream>>>(inputs, emb, ws, out);
    }
}